// Round 1
// baseline (15418.472 us; speedup 1.0000x reference)
//
#include <hip/hip_runtime.h>

#define VOCAB   30
#define EMBED   256
#define KVS     128
#define BATCH   128
#define T_ENC   1024
#define MAX_LEN 250
#define NTH     512

// One block per batch element. The whole 250-step recurrence runs inside the
// kernel; batches are independent so no inter-block communication is needed.
__global__ __launch_bounds__(NTH, 1) void decoder_kernel(
    const float* __restrict__ key,    // B,T_ENC,KVS
    const float* __restrict__ value,  // B,T_ENC,KVS
    const int*   __restrict__ y,      // B,MAX_LEN
    const float* __restrict__ emb,    // VOCAB,EMBED
    const float* __restrict__ W_ih,   // 4K, EMBED+KVS = 512x384
    const float* __restrict__ W_hh,   // 4K, KVS       = 512x128
    const float* __restrict__ b_ih,   // 512
    const float* __restrict__ b_hh,   // 512
    const float* __restrict__ b_cp,   // 30
    float* __restrict__ out)          // preds B*250*30, then attn 250*1024
{
  __shared__ float s_emb[VOCAB * EMBED];   // 30720 B
  __shared__ float s_x[EMBED + KVS];       // 384
  __shared__ float s_gates[4 * KVS];       // 512
  __shared__ float s_h[KVS];
  __shared__ float s_c[KVS];
  __shared__ float s_ctx[KVS];
  __shared__ float s_attn[T_ENC];          // unnormalized exp()
  __shared__ float s_part[4][KVS];
  __shared__ float s_red[16];
  __shared__ float s_bias[4 * KVS];        // b_ih + b_hh
  __shared__ float s_bcp[VOCAB];
  __shared__ int   s_y[MAX_LEN];

  const int b    = blockIdx.x;
  const int tid  = threadIdx.x;
  const int lane = tid & 63;
  const int wid  = tid >> 6;

  // ---- preload block-invariant data ----
  for (int i = tid; i < VOCAB * EMBED; i += NTH) s_emb[i] = emb[i];
  for (int i = tid; i < 4 * KVS; i += NTH)       s_bias[i] = b_ih[i] + b_hh[i];
  for (int i = tid; i < MAX_LEN; i += NTH)       s_y[i] = y[b * MAX_LEN + i];
  if (tid < VOCAB) s_bcp[tid] = b_cp[tid];
  if (tid < KVS) {
    s_h[tid] = 0.f;
    s_c[tid] = 0.f;
    s_ctx[tid] = value[(size_t)b * T_ENC * KVS + tid];  // value[b,0,:]
  }
  __syncthreads();

  const float* keyb = key   + (size_t)b * T_ENC * KVS;
  const float* valb = value + (size_t)b * T_ENC * KVS;
  const size_t PRED_SZ = (size_t)BATCH * MAX_LEN * VOCAB;

  for (int t = 0; t < MAX_LEN; ++t) {
    // ---- phase 1: build x = [char_embed, ctx] ----
    if (tid < EMBED) {
      s_x[tid] = (t == 0) ? 0.f : s_emb[s_y[t - 1] * EMBED + tid];
    } else if (tid < EMBED + KVS) {
      s_x[tid] = s_ctx[tid - EMBED];
    }
    __syncthreads();

    // ---- phase 2: gates[r] = W_ih[r].x + W_hh[r].h + bias[r] ----
    {
      const int r = tid;  // 512 rows, 512 threads
      const float4* wi = (const float4*)(W_ih + (size_t)r * (EMBED + KVS));
      const float4* wh = (const float4*)(W_hh + (size_t)r * KVS);
      float acc = s_bias[r];
      #pragma unroll 8
      for (int q = 0; q < (EMBED + KVS) / 4; ++q) {
        float4 w = wi[q];
        acc += w.x * s_x[4*q] + w.y * s_x[4*q+1] + w.z * s_x[4*q+2] + w.w * s_x[4*q+3];
      }
      #pragma unroll 8
      for (int q = 0; q < KVS / 4; ++q) {
        float4 w = wh[q];
        acc += w.x * s_h[4*q] + w.y * s_h[4*q+1] + w.z * s_h[4*q+2] + w.w * s_h[4*q+3];
      }
      s_gates[r] = acc;
    }
    __syncthreads();

    // ---- phase 3: LSTM cell update ----
    if (tid < KVS) {
      float ig = s_gates[tid];
      float fg = s_gates[KVS + tid];
      float gg = s_gates[2 * KVS + tid];
      float og = s_gates[3 * KVS + tid];
      float si = 1.f / (1.f + __expf(-ig));
      float sf = 1.f / (1.f + __expf(-fg));
      float so = 1.f / (1.f + __expf(-og));
      float c_new = sf * s_c[tid] + si * tanhf(gg);
      s_c[tid] = c_new;
      s_h[tid] = so * tanhf(c_new);
    }
    __syncthreads();

    // ---- phase 4: energy[t'] = key[b,t',:] . h  (2 rows per thread) ----
    float e0, e1;
    {
      const float4* kr0 = (const float4*)(keyb + (size_t)tid * KVS);
      const float4* kr1 = (const float4*)(keyb + (size_t)(tid + 512) * KVS);
      float a0 = 0.f, a1 = 0.f;
      #pragma unroll 8
      for (int q = 0; q < KVS / 4; ++q) {
        float4 k0 = kr0[q];
        float4 k1 = kr1[q];
        float h0 = s_h[4*q], h1 = s_h[4*q+1], h2 = s_h[4*q+2], h3 = s_h[4*q+3];
        a0 += k0.x * h0 + k0.y * h1 + k0.z * h2 + k0.w * h3;
        a1 += k1.x * h0 + k1.y * h1 + k1.z * h2 + k1.w * h3;
      }
      e0 = a0; e1 = a1;
    }
    // ---- phase 5: softmax over 1024 ----
    float m = fmaxf(e0, e1);
    #pragma unroll
    for (int off = 32; off; off >>= 1) m = fmaxf(m, __shfl_xor(m, off));
    if (lane == 0) s_red[wid] = m;
    __syncthreads();
    float M = s_red[0];
    #pragma unroll
    for (int w = 1; w < 8; ++w) M = fmaxf(M, s_red[w]);
    float p0 = __expf(e0 - M), p1 = __expf(e1 - M);
    s_attn[tid]       = p0;
    s_attn[tid + 512] = p1;
    float s = p0 + p1;
    #pragma unroll
    for (int off = 32; off; off >>= 1) s += __shfl_xor(s, off);
    if (lane == 0) s_red[8 + wid] = s;
    __syncthreads();
    float S = 0.f;
    #pragma unroll
    for (int w = 0; w < 8; ++w) S += s_red[8 + w];
    const float invS = 1.f / S;

    if (b == 0) {  // attentions output: attn row of batch 0
      out[PRED_SZ + (size_t)t * T_ENC + tid]       = p0 * invS;
      out[PRED_SZ + (size_t)t * T_ENC + tid + 512] = p1 * invS;
    }

    // ---- phase 6: ctx[k] = sum_t attn[t] * value[b,t,k] ----
    {
      const int k    = tid & (KVS - 1);
      const int part = tid >> 7;            // 4 T-partitions of 256
      const float* vb = valb + (size_t)part * 256 * KVS;
      const float* ap = s_attn + part * 256;
      float acc = 0.f;
      #pragma unroll 4
      for (int q = 0; q < 256; ++q) {
        acc += ap[q] * vb[(size_t)q * KVS + k];
      }
      s_part[part][k] = acc;
    }
    __syncthreads();
    if (tid < KVS) {
      s_ctx[tid] = (s_part[0][tid] + s_part[1][tid] + s_part[2][tid] + s_part[3][tid]) * invS;
    }
    __syncthreads();

    // ---- phase 7: pred[v] = [h,ctx] . emb[v,:] + b_cp[v] ----
    if (tid < 480) {
      const int v  = tid >> 4;   // 0..29
      const int sl = tid & 15;
      float acc = 0.f;
      #pragma unroll
      for (int q = 0; q < 16; ++q) {
        int e = sl * 16 + q;
        float oc = (e < KVS) ? s_h[e] : s_ctx[e - KVS];
        acc += oc * s_emb[v * EMBED + e];
      }
      #pragma unroll
      for (int off = 8; off; off >>= 1) acc += __shfl_xor(acc, off);
      if (sl == 0) out[((size_t)b * MAX_LEN + t) * VOCAB + v] = acc + s_bcp[v];
    }
    __syncthreads();
  }
}

extern "C" void kernel_launch(void* const* d_in, const int* in_sizes, int n_in,
                              void* d_out, int out_size, void* d_ws, size_t ws_size,
                              hipStream_t stream) {
  const float* key   = (const float*)d_in[0];
  const float* value = (const float*)d_in[1];
  // d_in[2] = encoder_len : unused by the reference computation
  const int*   y     = (const int*)d_in[3];
  const float* emb   = (const float*)d_in[4];
  const float* W_ih  = (const float*)d_in[5];
  const float* W_hh  = (const float*)d_in[6];
  const float* b_ih  = (const float*)d_in[7];
  const float* b_hh  = (const float*)d_in[8];
  const float* b_cp  = (const float*)d_in[9];
  float* out = (float*)d_out;

  decoder_kernel<<<BATCH, NTH, 0, stream>>>(key, value, y, emb, W_ih, W_hh,
                                            b_ih, b_hh, b_cp, out);
}

// Round 4
// 14230.797 us; speedup vs baseline: 1.0835x; 1.0835x over previous
//
#include <hip/hip_runtime.h>

#define VOCAB   30
#define EMBED   256
#define KVS     128
#define BATCH   128
#define T_ENC   1024
#define MAX_LEN 250
#define NTH     1024
#define HALF_T  512

__device__ __forceinline__ float dot4(float4 a, float4 b) {
  return a.x * b.x + a.y * b.y + a.z * b.z + a.w * b.w;
}
__device__ __forceinline__ void ws_store(float* p, float v) {
  __hip_atomic_store(p, v, __ATOMIC_RELAXED, __HIP_MEMORY_SCOPE_AGENT);
}
__device__ __forceinline__ float ws_load(const float* p) {
  return __hip_atomic_load(p, __ATOMIC_RELAXED, __HIP_MEMORY_SCOPE_AGENT);
}

// 2 blocks per batch (pair splits T_ENC in half); flash-style exact merge of
// softmax partials each step via d_ws + device-scope flags. All 256 blocks are
// co-resident (256 blocks <= capacity), so spin-wait cannot deadlock.
__global__ __launch_bounds__(NTH, 1) void decoder_kernel(
    const float* __restrict__ key,    // B,T_ENC,KVS
    const float* __restrict__ value,  // B,T_ENC,KVS
    const int*   __restrict__ y,      // B,MAX_LEN
    const float* __restrict__ emb,    // VOCAB,EMBED
    const float* __restrict__ W_ih,   // 512x384
    const float* __restrict__ W_hh,   // 512x128
    const float* __restrict__ b_ih,
    const float* __restrict__ b_hh,
    const float* __restrict__ b_cp,
    float* __restrict__ out,          // preds B*250*30, then attn 250*1024
    float* __restrict__ ws_msgs,      // [128][2 parity][2 half][130]
    int*   __restrict__ ws_flags)     // [128][2 parity][2 half]
{
  __shared__ float s_emb[VOCAB * EMBED];
  __shared__ __align__(16) float s_x[EMBED + KVS];
  __shared__ float s_gates[4 * KVS];
  __shared__ __align__(16) float s_h[KVS];
  __shared__ float s_c[KVS];
  __shared__ float s_ctx[KVS];
  __shared__ float s_attn[HALF_T];
  __shared__ float s_part[16][KVS];
  __shared__ float s_redm[16];
  __shared__ float s_reds[16];
  __shared__ float s_mrem[2];
  __shared__ float s_bias[4 * KVS];
  __shared__ float s_bcp[VOCAB];
  __shared__ int   s_y[MAX_LEN];

  const int b    = blockIdx.x >> 1;
  const int half = blockIdx.x & 1;
  const int tid  = threadIdx.x;
  const int lane = tid & 63;
  const int wid  = tid >> 6;

  for (int i = tid; i < VOCAB * EMBED; i += NTH) s_emb[i] = emb[i];
  for (int i = tid; i < 4 * KVS; i += NTH)       s_bias[i] = b_ih[i] + b_hh[i];
  for (int i = tid; i < MAX_LEN; i += NTH)       s_y[i] = y[b * MAX_LEN + i];
  if (tid < VOCAB) s_bcp[tid] = b_cp[tid];
  if (tid < KVS) {
    s_h[tid] = 0.f; s_c[tid] = 0.f;
    s_ctx[tid] = value[(size_t)b * T_ENC * KVS + tid];  // value[b,0,:] fp32 exact
  }
  __syncthreads();

  const float* keyb = key   + (size_t)b * T_ENC * KVS + (size_t)half * HALF_T * KVS;
  const float* valb = value + (size_t)b * T_ENC * KVS + (size_t)half * HALF_T * KVS;
  const size_t PRED_SZ = (size_t)BATCH * MAX_LEN * VOCAB;

  for (int t = 0; t < MAX_LEN; ++t) {
    const int par = t & 1;
    float* msg_out = ws_msgs + (size_t)(((b * 2 + par) * 2) + half) * 130;
    const float* msg_in = ws_msgs + (size_t)(((b * 2 + par) * 2) + (half ^ 1)) * 130;
    int* flag_out = ws_flags + ((b * 2 + par) * 2) + half;
    int* flag_in  = ws_flags + ((b * 2 + par) * 2) + (half ^ 1);

    // ---- phase 1: x = [char_embed, ctx] ----
    if (tid < EMBED) {
      s_x[tid] = (t == 0) ? 0.f : s_emb[s_y[t - 1] * EMBED + tid];
    } else if (tid < EMBED + KVS) {
      s_x[tid] = s_ctx[tid - EMBED];
    }
    __syncthreads();

    // ---- phase 2: gates (2 threads per row) ----
    {
      const int r = tid >> 1, hf = tid & 1;
      const float4* wi = (const float4*)(W_ih + (size_t)r * (EMBED + KVS) + hf * 192);
      const float4* wh = (const float4*)(W_hh + (size_t)r * KVS + hf * 64);
      const float4* xs = (const float4*)s_x + hf * 48;
      const float4* hs = (const float4*)s_h + hf * 16;
      float acc = hf ? 0.f : s_bias[r];
      #pragma unroll 12
      for (int q = 0; q < 48; ++q) acc += dot4(wi[q], xs[q]);
      #pragma unroll
      for (int q = 0; q < 16; ++q) acc += dot4(wh[q], hs[q]);
      acc += __shfl_xor(acc, 1);
      if (!hf) s_gates[r] = acc;
    }
    __syncthreads();

    // ---- phase 3: LSTM cell ----
    if (tid < KVS) {
      float ig = s_gates[tid], fg = s_gates[KVS + tid];
      float gg = s_gates[2 * KVS + tid], og = s_gates[3 * KVS + tid];
      float si = 1.f / (1.f + __expf(-ig));
      float sf = 1.f / (1.f + __expf(-fg));
      float so = 1.f / (1.f + __expf(-og));
      float cn = sf * s_c[tid] + si * tanhf(gg);
      s_c[tid] = cn;
      s_h[tid] = so * tanhf(cn);
    }
    __syncthreads();

    // ---- phase 4: energy over local 512 rows, wave-cooperative coalesced ----
    {
      const int sub = lane & 7, rl = lane >> 3;
      const float4* h4 = (const float4*)s_h + sub * 4;
      #pragma unroll
      for (int P = 0; P < 4; ++P) {
        const int row = wid * 32 + P * 8 + rl;
        const float4* kr = (const float4*)(keyb + (size_t)row * KVS + sub * 16);
        float a = dot4(kr[0], h4[0]) + dot4(kr[1], h4[1]) +
                  dot4(kr[2], h4[2]) + dot4(kr[3], h4[3]);
        a += __shfl_xor(a, 1);
        a += __shfl_xor(a, 2);
        a += __shfl_xor(a, 4);
        if (sub == 0) s_attn[row] = a;
      }
    }
    __syncthreads();

    // ---- phase 5: local softmax stats (m_loc, l_loc), p into s_attn ----
    float p_loc, m_loc, l_loc;
    {
      const float e = (tid < HALF_T) ? s_attn[tid] : -1e30f;
      float mm = e;
      #pragma unroll
      for (int o = 32; o; o >>= 1) mm = fmaxf(mm, __shfl_xor(mm, o));
      if (lane == 0) s_redm[wid] = mm;
      __syncthreads();
      m_loc = s_redm[0];
      #pragma unroll
      for (int w = 1; w < 16; ++w) m_loc = fmaxf(m_loc, s_redm[w]);
      float p = (tid < HALF_T) ? __expf(e - m_loc) : 0.f;
      p_loc = p;
      if (tid < HALF_T) s_attn[tid] = p;
      float ss = p;
      #pragma unroll
      for (int o = 32; o; o >>= 1) ss += __shfl_xor(ss, o);
      if (lane == 0) s_reds[wid] = ss;
      __syncthreads();
      l_loc = 0.f;
      #pragma unroll
      for (int w = 0; w < 16; ++w) l_loc += s_reds[w];
    }

    // ---- phase 6: local ctx partial (unnormalized) ----
    {
      const int kk = (tid & 63) * 2;
      const int part = tid >> 6;  // 16 parts x 32 rows
      const float* vb = valb + (size_t)part * 32 * KVS + kk;
      float ax = 0.f, ay = 0.f;
      #pragma unroll 8
      for (int q = 0; q < 32; ++q) {
        const float w = s_attn[part * 32 + q];
        const float2 v2 = *(const float2*)(vb + (size_t)q * KVS);
        ax += w * v2.x; ay += w * v2.y;
      }
      s_part[part][kk] = ax; s_part[part][kk + 1] = ay;
    }
    __syncthreads();
    float ctxp = 0.f;
    if (tid < KVS) {
      #pragma unroll
      for (int p2 = 0; p2 < 16; ++p2) ctxp += s_part[p2][tid];
    }

    // ---- phase 7: exchange partials with partner block ----
    if (tid < KVS)      ws_store(msg_out + 2 + tid, ctxp);
    if (tid == KVS)     ws_store(msg_out + 0, m_loc);
    if (tid == KVS + 1) ws_store(msg_out + 1, l_loc);
    __syncthreads();  // compiler drains vmcnt before s_barrier -> stores visible
    if (tid == 0) {
      __hip_atomic_store(flag_out, t + 1, __ATOMIC_RELEASE, __HIP_MEMORY_SCOPE_AGENT);
      while (__hip_atomic_load(flag_in, __ATOMIC_ACQUIRE, __HIP_MEMORY_SCOPE_AGENT) < t + 1) {}
      s_mrem[0] = ws_load(msg_in + 0);
      s_mrem[1] = ws_load(msg_in + 1);
    }
    __syncthreads();
    const float m_rem = s_mrem[0], l_rem = s_mrem[1];
    const float M     = fmaxf(m_loc, m_rem);
    const float w_loc = __expf(m_loc - M), w_rem = __expf(m_rem - M);
    const float S     = w_loc * l_loc + w_rem * l_rem;
    const float invS  = 1.f / S;
    if (tid < KVS) {
      const float cr = ws_load(msg_in + 2 + tid);
      s_ctx[tid] = (w_loc * ctxp + w_rem * cr) * invS;
    }
    if (b == 0 && tid < HALF_T) {
      out[PRED_SZ + (size_t)t * T_ENC + half * HALF_T + tid] = p_loc * w_loc * invS;
    }
    __syncthreads();

    // ---- phase 8: pred (half 0 writes) ----
    if (half == 0 && tid < 480) {
      const int v = tid >> 4, sl = tid & 15;
      float acc = 0.f;
      #pragma unroll
      for (int q = 0; q < 16; ++q) {
        const int e2 = sl * 16 + q;
        const float oc = (e2 < KVS) ? s_h[e2] : s_ctx[e2 - KVS];
        acc += oc * s_emb[v * EMBED + e2];
      }
      #pragma unroll
      for (int o = 8; o; o >>= 1) acc += __shfl_xor(acc, o);
      if (sl == 0) out[((size_t)b * MAX_LEN + t) * VOCAB + v] = acc + s_bcp[v];
    }
    __syncthreads();
  }
}

extern "C" void kernel_launch(void* const* d_in, const int* in_sizes, int n_in,
                              void* d_out, int out_size, void* d_ws, size_t ws_size,
                              hipStream_t stream) {
  const float* key   = (const float*)d_in[0];
  const float* value = (const float*)d_in[1];
  // d_in[2] = encoder_len : unused by the reference computation
  const int*   y     = (const int*)d_in[3];
  const float* emb   = (const float*)d_in[4];
  const float* W_ih  = (const float*)d_in[5];
  const float* W_hh  = (const float*)d_in[6];
  const float* b_ih  = (const float*)d_in[7];
  const float* b_hh  = (const float*)d_in[8];
  const float* b_cp  = (const float*)d_in[9];
  float* out = (float*)d_out;

  int*   flags = (int*)d_ws;                     // 128*2*2*4 = 2 KB (zeroed below)
  float* msgs  = (float*)((char*)d_ws + 4096);   // 128*2*2*130*4 = 260 KB

  hipMemsetAsync(d_ws, 0, 4096, stream);
  decoder_kernel<<<2 * BATCH, NTH, 0, stream>>>(key, value, y, emb, W_ih, W_hh,
                                                b_ih, b_hh, b_cp, out, msgs, flags);
}

// Round 5
// 9560.490 us; speedup vs baseline: 1.6127x; 1.4885x over previous
//
#include <hip/hip_runtime.h>

#define VOCAB   30
#define EMBED   256
#define KVS     128
#define BATCH   128
#define T_ENC   1024
#define MAX_LEN 250
#define NTH     1024
#define HALF_T  512

__device__ __forceinline__ float dot4(float4 a, float4 b) {
  return a.x * b.x + a.y * b.y + a.z * b.z + a.w * b.w;
}
__device__ __forceinline__ void ws_store(float* p, float v) {
  __hip_atomic_store(p, v, __ATOMIC_RELAXED, __HIP_MEMORY_SCOPE_AGENT);
}
__device__ __forceinline__ float ws_load(const float* p) {
  return __hip_atomic_load(p, __ATOMIC_RELAXED, __HIP_MEMORY_SCOPE_AGENT);
}

// 2 blocks per batch (same-XCD pair via bid swizzle). LSTM cells j-split across
// the pair; recurrent weights (256 rows x 256 cols fp32 = 64 VGPR/thread) live
// in registers; the embedding contribution to the gates is a 30-entry
// precomputed table (G = W_emb*emb[v] + bias) in LDS. Zero per-step weight
// traffic. Two flash-style handshakes/step: A = h halves, B = softmax/ctx.
__global__ __launch_bounds__(NTH, 4) void decoder_kernel(
    const float* __restrict__ key,    // B,T_ENC,KVS
    const float* __restrict__ value,  // B,T_ENC,KVS
    const int*   __restrict__ y,      // B,MAX_LEN
    const float* __restrict__ emb,    // VOCAB,EMBED
    const float* __restrict__ W_ih,   // 512x384
    const float* __restrict__ W_hh,   // 512x128
    const float* __restrict__ b_ih,
    const float* __restrict__ b_hh,
    const float* __restrict__ b_cp,
    float* __restrict__ out,          // preds B*250*30, then attn 250*1024
    float* __restrict__ msgsA,        // [128][2 par][2 half][64]
    float* __restrict__ msgsB,        // [128][2 par][2 half][130]
    int*   __restrict__ flags)        // [128][2 par][2 phase][2 half]
{
  __shared__ float s_G[VOCAB * 256];          // gate-emb table (own 256 rows)
  __shared__ __align__(16) float s_emb[VOCAB * EMBED];
  __shared__ __align__(16) float s_rec[256];  // [ctx(128), h(128)]
  __shared__ float s_gates[256];
  __shared__ float s_c[64];
  __shared__ float s_attn[HALF_T];
  __shared__ float s_part[16][KVS];
  __shared__ float s_redm[16];
  __shared__ float s_reds[16];
  __shared__ float s_stats[2];
  __shared__ float s_biasloc[256];
  __shared__ float s_bcp[VOCAB];
  __shared__ int   s_y[MAX_LEN];

  const int bid  = blockIdx.x;
  const int half = (bid >> 3) & 1;                  // pair partners share bid%8 -> same XCD
  const int b    = (bid & 7) | ((bid >> 4) << 3);
  const int tid  = threadIdx.x;
  const int lane = tid & 63;
  const int wid  = tid >> 6;
  const int rloc = tid >> 2;     // local gate row 0..255
  const int q    = tid & 3;      // col-quad within row

  // ---- prologue: shared loads ----
  for (int i = tid; i < VOCAB * EMBED; i += NTH) s_emb[i] = emb[i];
  for (int i = tid; i < MAX_LEN; i += NTH)       s_y[i] = y[b * MAX_LEN + i];
  if (tid < VOCAB) s_bcp[tid] = b_cp[tid];
  if (tid < 256) {
    const int g2 = tid >> 6, j2 = tid & 63;
    const int gr2 = g2 * 128 + half * 64 + j2;
    s_biasloc[tid] = b_ih[gr2] + b_hh[gr2];
  }
  if (tid < KVS) {
    s_rec[tid] = value[(size_t)b * T_ENC * KVS + tid];  // ctx0 = value[b,0,:]
    s_rec[128 + tid] = 0.f;                             // h0 = 0
  }
  if (tid < 64) s_c[tid] = 0.f;
  __syncthreads();

  const int gate = rloc >> 6, jj = rloc & 63;
  const int grow = gate * 128 + half * 64 + jj;   // global gate row
  const float4* Wih4 = (const float4*)W_ih;       // row stride 96 float4
  const float4* Whh4 = (const float4*)W_hh;       // row stride 32 float4

  // ---- prologue: G table (W_emb * emb[v] + bias), own rows only ----
  {
    float4 we[16];
    #pragma unroll
    for (int k = 0; k < 16; ++k) we[k] = Wih4[(size_t)grow * 96 + 4 * k + q];
    const float4* se4 = (const float4*)s_emb;
    for (int v = 0; v < VOCAB; ++v) {
      float a = 0.f;
      #pragma unroll
      for (int k = 0; k < 16; ++k) a += dot4(we[k], se4[v * 64 + 4 * k + q]);
      a += __shfl_xor(a, 1);
      a += __shfl_xor(a, 2);
      if (q == 0) s_G[v * 256 + rloc] = a + s_biasloc[rloc];
    }
  }

  // ---- prologue: recurrent weights into registers (64 VGPR) ----
  // cols [ctx(128) | h(128)], interleaved float4: thread q holds f4 indices 4k+q
  float4 w4[16];
  #pragma unroll
  for (int k = 0; k < 8; ++k)
    w4[k] = Wih4[(size_t)grow * 96 + 64 + 4 * k + q];      // ctx cols of W_ih
  #pragma unroll
  for (int k = 8; k < 16; ++k)
    w4[k] = Whh4[(size_t)grow * 32 + 4 * (k - 8) + q];     // W_hh
  __syncthreads();

  const float* keyb = key   + (size_t)b * T_ENC * KVS + (size_t)half * HALF_T * KVS;
  const float* valb = value + (size_t)b * T_ENC * KVS + (size_t)half * HALF_T * KVS;
  const size_t PRED_SZ = (size_t)BATCH * MAX_LEN * VOCAB;
  const float4* sr4 = (const float4*)s_rec;

  for (int t = 0; t < MAX_LEN; ++t) {
    const int par = t & 1;
    float*       msgA_out = msgsA + (size_t)(((b * 2 + par) * 2) + half) * 64;
    const float* msgA_in  = msgsA + (size_t)(((b * 2 + par) * 2) + (half ^ 1)) * 64;
    float*       msgB_out = msgsB + (size_t)(((b * 2 + par) * 2) + half) * 130;
    const float* msgB_in  = msgsB + (size_t)(((b * 2 + par) * 2) + (half ^ 1)) * 130;
    int* flagA_out = flags + (((b * 2 + par) * 2 + 0) * 2) + half;
    int* flagA_in  = flags + (((b * 2 + par) * 2 + 0) * 2) + (half ^ 1);
    int* flagB_out = flags + (((b * 2 + par) * 2 + 1) * 2) + half;
    int* flagB_in  = flags + (((b * 2 + par) * 2 + 1) * 2) + (half ^ 1);

    // ---- gates: G[yprev] + Wreg * [ctx,h]  (weights in registers) ----
    {
      const float* Gsrc = (t == 0) ? s_biasloc : (s_G + s_y[t - 1] * 256);
      float a = 0.f;
      #pragma unroll
      for (int k = 0; k < 16; ++k) a += dot4(w4[k], sr4[4 * k + q]);
      a += __shfl_xor(a, 1);
      a += __shfl_xor(a, 2);
      if (q == 0) s_gates[rloc] = a + Gsrc[rloc];
    }
    __syncthreads();

    // ---- LSTM cell update (own 64 cells) + publish h ----
    if (tid < 64) {
      float ig = s_gates[tid], fg = s_gates[64 + tid];
      float gg = s_gates[128 + tid], og = s_gates[192 + tid];
      float si = 1.f / (1.f + __expf(-ig));
      float sf = 1.f / (1.f + __expf(-fg));
      float so = 1.f / (1.f + __expf(-og));
      float cn = sf * s_c[tid] + si * tanhf(gg);
      s_c[tid] = cn;
      float hn = so * tanhf(cn);
      s_rec[128 + half * 64 + tid] = hn;
      ws_store(msgA_out + tid, hn);
    }
    __syncthreads();
    // ---- handshake A: exchange h halves ----
    if (tid == 0) {
      __hip_atomic_store(flagA_out, t + 1, __ATOMIC_RELEASE, __HIP_MEMORY_SCOPE_AGENT);
      while (__hip_atomic_load(flagA_in, __ATOMIC_ACQUIRE, __HIP_MEMORY_SCOPE_AGENT) < t + 1) {}
    }
    __syncthreads();
    if (tid < 64) s_rec[128 + (half ^ 1) * 64 + tid] = ws_load(msgA_in + tid);
    __syncthreads();

    // ---- energy over local 512 K-rows (wave-cooperative, coalesced) ----
    {
      const int sub = lane & 7, rl = lane >> 3;
      const float4* h4 = (const float4*)(s_rec + 128) + sub * 4;
      #pragma unroll
      for (int P = 0; P < 4; ++P) {
        const int row = wid * 32 + P * 8 + rl;
        const float4* kr = (const float4*)(keyb + (size_t)row * KVS + sub * 16);
        float a = dot4(kr[0], h4[0]) + dot4(kr[1], h4[1]) +
                  dot4(kr[2], h4[2]) + dot4(kr[3], h4[3]);
        a += __shfl_xor(a, 1);
        a += __shfl_xor(a, 2);
        a += __shfl_xor(a, 4);
        if (sub == 0) s_attn[row] = a;
      }
    }
    __syncthreads();

    // ---- local softmax stats ----
    float p_loc, m_loc, l_loc;
    {
      const float e = (tid < HALF_T) ? s_attn[tid] : -1e30f;
      float mm = e;
      #pragma unroll
      for (int o = 32; o; o >>= 1) mm = fmaxf(mm, __shfl_xor(mm, o));
      if (lane == 0) s_redm[wid] = mm;
      __syncthreads();
      m_loc = s_redm[0];
      #pragma unroll
      for (int w = 1; w < 16; ++w) m_loc = fmaxf(m_loc, s_redm[w]);
      float p = (tid < HALF_T) ? __expf(e - m_loc) : 0.f;
      p_loc = p;
      if (tid < HALF_T) s_attn[tid] = p;
      float ss = p;
      #pragma unroll
      for (int o = 32; o; o >>= 1) ss += __shfl_xor(ss, o);
      if (lane == 0) s_reds[wid] = ss;
      __syncthreads();
      l_loc = 0.f;
      #pragma unroll
      for (int w = 0; w < 16; ++w) l_loc += s_reds[w];
    }

    // ---- local ctx partial (unnormalized) ----
    {
      const int kk = (tid & 63) * 2;
      const int part = tid >> 6;  // 16 parts x 32 rows
      const float* vb = valb + (size_t)part * 32 * KVS + kk;
      float ax = 0.f, ay = 0.f;
      #pragma unroll 8
      for (int q2 = 0; q2 < 32; ++q2) {
        const float w = s_attn[part * 32 + q2];
        const float2 v2 = *(const float2*)(vb + (size_t)q2 * KVS);
        ax += w * v2.x; ay += w * v2.y;
      }
      s_part[part][kk] = ax; s_part[part][kk + 1] = ay;
    }
    __syncthreads();
    float ctxp = 0.f;
    if (tid < KVS) {
      #pragma unroll
      for (int p2 = 0; p2 < 16; ++p2) ctxp += s_part[p2][tid];
    }

    // ---- handshake B: merge softmax partials ----
    if (tid < KVS)      ws_store(msgB_out + 2 + tid, ctxp);
    if (tid == KVS)     ws_store(msgB_out + 0, m_loc);
    if (tid == KVS + 1) ws_store(msgB_out + 1, l_loc);
    __syncthreads();
    if (tid == 0) {
      __hip_atomic_store(flagB_out, t + 1, __ATOMIC_RELEASE, __HIP_MEMORY_SCOPE_AGENT);
      while (__hip_atomic_load(flagB_in, __ATOMIC_ACQUIRE, __HIP_MEMORY_SCOPE_AGENT) < t + 1) {}
      s_stats[0] = ws_load(msgB_in + 0);
      s_stats[1] = ws_load(msgB_in + 1);
    }
    __syncthreads();
    const float m_rem = s_stats[0], l_rem = s_stats[1];
    // fixed half-order merge => bitwise-identical ctx across the pair
    const float mA = half ? m_rem : m_loc, mB = half ? m_loc : m_rem;
    const float lA = half ? l_rem : l_loc, lB = half ? l_loc : l_rem;
    const float M  = fmaxf(mA, mB);
    const float wA = __expf(mA - M), wB = __expf(mB - M);
    const float S  = wA * lA + wB * lB;
    const float invS = 1.f / S;
    const float w_own = half ? wB : wA;
    if (tid < KVS) {
      const float cr = ws_load(msgB_in + 2 + tid);
      const float cA = half ? cr : ctxp, cB = half ? ctxp : cr;
      s_rec[tid] = (wA * cA + wB * cB) * invS;
    }
    if (b == 0 && tid < HALF_T) {
      out[PRED_SZ + (size_t)t * T_ENC + half * HALF_T + tid] = p_loc * w_own * invS;
    }
    __syncthreads();

    // ---- pred (half 0 only) ----
    if (half == 0 && tid < 480) {
      const int v = tid >> 4, sl = tid & 15;
      float acc = 0.f;
      #pragma unroll
      for (int q2 = 0; q2 < 16; ++q2) {
        const int e2 = sl * 16 + q2;
        const float oc = (e2 < KVS) ? s_rec[128 + e2] : s_rec[e2 - KVS];
        acc += oc * s_emb[v * EMBED + e2];
      }
      #pragma unroll
      for (int o = 8; o; o >>= 1) acc += __shfl_xor(acc, o);
      if (sl == 0) out[((size_t)b * MAX_LEN + t) * VOCAB + v] = acc + s_bcp[v];
    }
    // no barrier needed: next-iteration reads (s_rec, s_G) are stable; s_gates
    // WAR is separated by the next gates-phase barrier.
  }
}

extern "C" void kernel_launch(void* const* d_in, const int* in_sizes, int n_in,
                              void* d_out, int out_size, void* d_ws, size_t ws_size,
                              hipStream_t stream) {
  const float* key   = (const float*)d_in[0];
  const float* value = (const float*)d_in[1];
  // d_in[2] = encoder_len : unused by the reference computation
  const int*   y     = (const int*)d_in[3];
  const float* emb   = (const float*)d_in[4];
  const float* W_ih  = (const float*)d_in[5];
  const float* W_hh  = (const float*)d_in[6];
  const float* b_ih  = (const float*)d_in[7];
  const float* b_hh  = (const float*)d_in[8];
  const float* b_cp  = (const float*)d_in[9];
  float* out = (float*)d_out;

  int*   flags = (int*)d_ws;                               // 4 KB used
  float* msgsA = (float*)((char*)d_ws + 8192);             // 128*2*2*64*4  = 128 KB
  float* msgsB = (float*)((char*)d_ws + 8192 + 131072);    // 128*2*2*130*4 = 260 KB

  hipMemsetAsync(d_ws, 0, 8192, stream);
  decoder_kernel<<<2 * BATCH, NTH, 0, stream>>>(key, value, y, emb, W_ih, W_hh,
                                                b_ih, b_hh, b_cp, out,
                                                msgsA, msgsB, flags);
}